// Round 4
// baseline (503.606 us; speedup 1.0000x reference)
//
#include <hip/hip_runtime.h>
#include <hip/hip_bf16.h>
#include <stdint.h>

typedef __attribute__((ext_vector_type(4)))  float f32x4;
typedef __attribute__((ext_vector_type(16))) float f32x16;
typedef __attribute__((ext_vector_type(8)))  short short8v;

typedef __attribute__((address_space(1))) void gvoid;
typedef __attribute__((address_space(3))) void lvoid;

#define GLD16(gp, lp) __builtin_amdgcn_global_load_lds((const gvoid*)(gp), (lvoid*)(lp), 16, 0, 0)

__device__ __forceinline__ unsigned short f2bf(float f) {
    union { float ff; unsigned uu; } a; a.ff = f;
    unsigned u = a.uu;
    u += 0x7FFFu + ((u >> 16) & 1u);   // RNE; inputs finite
    return (unsigned short)(u >> 16);
}

// ---- Ub[o][r] = bf16(U[o][r] * (S[r]+eps[r])), row-major [4096][4096] ----
__global__ __launch_bounds__(256) void prep_u_kernel(
    const float* __restrict__ U, const float* __restrict__ S,
    const float* __restrict__ eps, unsigned short* __restrict__ Ub) {
    long idx = ((long)blockIdx.x * 256 + threadIdx.x) * 8;
    int r = (int)(idx & 4095);
    f32x4 u0 = *(const f32x4*)(U + idx);
    f32x4 u1 = *(const f32x4*)(U + idx + 4);
    f32x4 s0 = *(const f32x4*)(S + r);
    f32x4 s1 = *(const f32x4*)(S + r + 4);
    f32x4 e0 = *(const f32x4*)(eps + r);
    f32x4 e1 = *(const f32x4*)(eps + r + 4);
    union { uint4 v; unsigned short s[8]; } o;
#pragma unroll
    for (int j = 0; j < 4; ++j) {
        o.s[j]     = f2bf(u0[j] * (s0[j] + e0[j]));
        o.s[j + 4] = f2bf(u1[j] * (s1[j] + e1[j]));
    }
    *(uint4*)(Ub + idx) = o.v;
}

// ---- generic fp32 -> bf16 convert, 8 elems/thread ----
__global__ __launch_bounds__(256) void cvt_bf16_kernel(
    const float* __restrict__ src, unsigned short* __restrict__ dst) {
    long idx = ((long)blockIdx.x * 256 + threadIdx.x) * 8;
    f32x4 v0 = *(const f32x4*)(src + idx);
    f32x4 v1 = *(const f32x4*)(src + idx + 4);
    union { uint4 v; unsigned short s[8]; } o;
#pragma unroll
    for (int j = 0; j < 4; ++j) {
        o.s[j]     = f2bf(v0[j]);
        o.s[j + 4] = f2bf(v1[j]);
    }
    *(uint4*)(dst + idx) = o.v;
}

// ---- VtT[k][r] = bf16(Vt[r][k]); 64x64 tiles, padded LDS (conflict-free) ----
__global__ __launch_bounds__(256) void transpose_cvt_kernel(
    const float* __restrict__ src, unsigned short* __restrict__ dst) {
    __shared__ float tile[64][65];
    int tx = threadIdx.x & 63;
    int tq = threadIdx.x >> 6;
    int r0 = blockIdx.y << 6;
    int k0 = blockIdx.x << 6;
#pragma unroll
    for (int i = 0; i < 16; ++i) {
        int row = (i << 2) + tq;
        tile[row][tx] = src[(long)(r0 + row) * 4096 + k0 + tx];
    }
    __syncthreads();
#pragma unroll
    for (int i = 0; i < 16; ++i) {
        int krow = (i << 2) + tq;
        dst[(long)(k0 + krow) * 4096 + r0 + tx] = f2bf(tile[tx][krow]);
    }
}

// =====================================================================
// 256x256-tile 4-phase NT GEMM, 32x32x16 MFMA.
// C[M][N] = A[M][K] * B[N][K]^T (+bias). bf16 in, fp32 acc.
// 512 thr = 8 waves (2M x 4N), wave tile 128x64.
// LDS physical layout UNCHANGED from the verified round-3 kernel:
//   per matrix 2 buf x 2 k-half chunks of [256 rows][32 k] bf16,
//   XOR swizzle slot ^= (row>>1)&3, staged linearly by global_load_lds
//   with inverse-swizzled global source (rule 21; 0 conflicts measured).
// Change: mfma_f32_32x32x16_bf16 (2x FLOP/instr, +15% pipe ceiling) ->
// 4 phases/iter (was 8), 16 MFMA each, barriers halved. Uniform counted
// vmcnt(8) per phase drains exactly the 3-phase-old stage (never 0).
// =====================================================================
#define MM32(a, b, c) __builtin_amdgcn_mfma_f32_32x32x16_bf16(a, b, c, 0, 0, 0)

#define ACH(bf, kh) (As + ((bf) * 2 + (kh)) * 8192)
#define BCH(bf, kh) (Bs + ((bf) * 2 + (kh)) * 8192)

#define STAGE_A(bf, kh, koff) do { \
    const unsigned short* _s = A + gAr + (koff); \
    unsigned short* _d = ACH(bf, kh) + wave * 512; \
    GLD16(_s, _d); GLD16(_s + (long)128 * K, _d + 4096); } while (0)

#define STAGE_B(bf, kh, koff) do { \
    const unsigned short* _s = B + gBr + (koff); \
    unsigned short* _d = BCH(bf, kh) + wave * 512; \
    GLD16(_s, _d); GLD16(_s + (long)128 * K, _d + 4096); } while (0)

// A-frags for one chunk, both k-steps: 8 x ds_read_b128
#define LDA32(bf, kh) do { \
    const unsigned short* _p = ACH(bf, kh) + aRowB; \
    _Pragma("unroll") \
    for (int _m = 0; _m < 4; ++_m) { \
        aR[0][_m] = *(const short8v*)(_p + _m * 1024 + sl0); \
        aR[1][_m] = *(const short8v*)(_p + _m * 1024 + sl1); } } while (0)

// B-frags for one chunk, both k-steps: 4 x ds_read_b128
#define LDB32(bf, kh) do { \
    const unsigned short* _p = BCH(bf, kh) + bRowB; \
    _Pragma("unroll") \
    for (int _n = 0; _n < 2; ++_n) { \
        bR[0][_n] = *(const short8v*)(_p + _n * 1024 + sl0); \
        bR[1][_n] = *(const short8v*)(_p + _n * 1024 + sl1); } } while (0)

#define PH_SYNC do { \
    __builtin_amdgcn_s_barrier(); \
    asm volatile("s_waitcnt lgkmcnt(0)" ::: "memory"); \
    __builtin_amdgcn_sched_barrier(0); } while (0)

#define MFMA32 do { \
    __builtin_amdgcn_s_setprio(1); \
    _Pragma("unroll") \
    for (int _ks = 0; _ks < 2; ++_ks) \
    _Pragma("unroll") \
    for (int _m = 0; _m < 4; ++_m) { \
        acc[_m][0] = MM32(aR[_ks][_m], bR[_ks][0], acc[_m][0]); \
        acc[_m][1] = MM32(aR[_ks][_m], bR[_ks][1], acc[_m][1]); \
    } \
    __builtin_amdgcn_s_setprio(0); } while (0)

#define VM8 asm volatile("s_waitcnt vmcnt(8)" ::: "memory")
#define PH_END __builtin_amdgcn_s_barrier()

template<int OUT_BF16, int BIAS>
__global__ __launch_bounds__(512, 2) void gemm256_kernel(
    const unsigned short* __restrict__ A,   // [M][K] bf16 bits
    const unsigned short* __restrict__ B,   // [N][K] bf16 bits
    void* __restrict__ Cv, const float* __restrict__ bias,
    int M, int N, int K) {
    __shared__ unsigned short As[4 * 8192];   // 64 KB
    __shared__ unsigned short Bs[4 * 8192];   // 64 KB

    const int tid  = threadIdx.x;
    const int wave = tid >> 6;
    const int lane = tid & 63;
    const int l5   = lane & 31;
    const int hi   = lane >> 5;

    // XCD-aware bijective swizzle (nwg % 8 == 0 for all launches)
    const int nwg = gridDim.x;
    const int bid = blockIdx.x;
    const int cpx = nwg >> 3;
    const int wg  = (bid & 7) * cpx + (bid >> 3);
    const int ntn = N >> 8;
    const long m0 = (long)(wg / ntn) << 8;
    const long n0 = (long)(wg % ntn) << 8;

    const int wwr = wave >> 2;   // 0..1  (M half)
    const int wwc = wave & 3;    // 0..3  (N quarter)

    // Stage addressing (UNCHANGED, verified): chunk [256 rows][32 k],
    // 1024 slots of 16B; global src slot = (si&3) ^ ((row>>1)&3).
    const int  rS  = tid >> 2;
    const int  sS  = (tid & 3) ^ ((rS >> 1) & 3);
    const long gAr = (m0 + rS) * K + sS * 8;
    const long gBr = (n0 + rS) * K + sS * 8;

    // 32x32x16 frag reads: lane -> row base+l5, k = hi*8 within k-step.
    // In-row 16B slot = ks*2 + hi, XOR'd by (row>>1)&3 == (l5>>1)&3.
    const int swz5 = (l5 >> 1) & 3;
    const int sl0  = ((0 + hi) ^ swz5) * 8;   // ks=0
    const int sl1  = ((2 + hi) ^ swz5) * 8;   // ks=1
    const int aRowB = (wwr * 128 + l5) * 32;
    const int bRowB = (wwc * 64 + l5) * 32;

    f32x16  acc[4][2] = {};
    short8v aR[2][4], bR[2][2];

    // Prologue: buf0.kh0, buf0.kh1, buf1.kh0 (A+B each = 4 loads).
    STAGE_A(0, 0, 0);  STAGE_B(0, 0, 0);
    STAGE_A(0, 1, 32); STAGE_B(0, 1, 32);
    STAGE_A(1, 0, 64); STAGE_B(1, 0, 64);
    VM8;                         // buf0.kh0 landed
    __builtin_amdgcn_s_barrier();

    const int nIter = K >> 7;    // 2 K-tiles (BK=64) per iteration
    for (int i = 0; i < nIter; ++i) {
        const int kA = 128 * i + 96;                  // buf1.kh1 (in-bounds)
        int k3 = 128 * i + 128; if (k3 >= K) k3 -= K; // next buf0.kh0 (wrap: dead)
        int k5 = 128 * i + 160; if (k5 >= K) k5 -= K; // next buf0.kh1
        int k7 = 128 * i + 192; if (k7 >= K) k7 -= K; // next buf1.kh0

        LDA32(0, 0); LDB32(0, 0); STAGE_A(1, 1, kA); STAGE_B(1, 1, kA);   // P1
        PH_SYNC; MFMA32; VM8; PH_END;
        LDA32(0, 1); LDB32(0, 1); STAGE_A(0, 0, k3); STAGE_B(0, 0, k3);   // P2
        PH_SYNC; MFMA32; VM8; PH_END;
        LDA32(1, 0); LDB32(1, 0); STAGE_A(0, 1, k5); STAGE_B(0, 1, k5);   // P3
        PH_SYNC; MFMA32; VM8; PH_END;
        LDA32(1, 1); LDB32(1, 1); STAGE_A(1, 0, k7); STAGE_B(1, 0, k7);   // P4
        PH_SYNC; MFMA32; VM8; PH_END;
    }

    // Epilogue: 32x32 C/D layout (m74/m101): col = lane&31,
    // row = (reg&3) + 8*(reg>>2) + 4*(lane>>5)
#pragma unroll
    for (int nf = 0; nf < 2; ++nf) {
        const int col = (int)n0 + wwc * 64 + nf * 32 + l5;
        float bv = BIAS ? bias[col] : 0.0f;
#pragma unroll
        for (int mf = 0; mf < 4; ++mf) {
            f32x16 v = acc[mf][nf];
            const long rb = m0 + wwr * 128 + mf * 32 + hi * 4;
#pragma unroll
            for (int r = 0; r < 16; ++r) {
                long row = rb + (r & 3) + 8 * (r >> 2);
                float val = v[r] + bv;
                long off = row * N + col;
                if (OUT_BF16) ((unsigned short*)Cv)[off] = f2bf(val);
                else          ((float*)Cv)[off] = val;
            }
        }
    }
}

extern "C" void kernel_launch(void* const* d_in, const int* in_sizes, int n_in,
                              void* d_out, int out_size, void* d_ws, size_t ws_size,
                              hipStream_t stream) {
    const float* x    = (const float*)d_in[0];   // [4,2048,4096] = [8192][4096]
    const float* U    = (const float*)d_in[1];   // [4096][4096]
    const float* S    = (const float*)d_in[2];   // [4096]
    const float* Vt   = (const float*)d_in[3];   // [4096][4096]
    const float* eps  = (const float*)d_in[4];   // [4096]
    const float* bias = (const float*)d_in[5];   // [4096]
    float* out = (float*)d_out;                  // [8192][4096] fp32

    char* ws = (char*)d_ws;
    unsigned short* Ub  = (unsigned short*)(ws);                       // 32 MB
    unsigned short* VtT = (unsigned short*)(ws + (size_t)(32 << 20));  // 32 MB
    unsigned short* Wb  = (unsigned short*)(ws + (size_t)(64 << 20));  // 32 MB
    unsigned short* Xb  = (unsigned short*)(ws);  // 64 MB, reuses Ub+VtT after GEMM1

    // 1) Ub = bf16(U * (S+eps))            [o][r]
    prep_u_kernel<<<8192, 256, 0, stream>>>(U, S, eps, Ub);
    // 2) VtT = bf16(Vt^T)                  [k][r]
    transpose_cvt_kernel<<<dim3(64, 64), 256, 0, stream>>>(Vt, VtT);
    // 3) Wb[o][k] = Ub @ VtT^T             (NT, K=r)  -> 256 wg
    gemm256_kernel<1, 0><<<256, 512, 0, stream>>>(Ub, VtT, (void*)Wb, nullptr,
                                                  4096, 4096, 4096);
    // 4) Xb = bf16(x)                      [m][k]  (overwrites Ub/VtT — now dead)
    cvt_bf16_kernel<<<16384, 256, 0, stream>>>(x, Xb);
    // 5) out[m][o] = Xb @ Wb^T + bias      (NT, K=k)  -> 512 wg
    gemm256_kernel<0, 1><<<512, 512, 0, stream>>>(Xb, Wb, (void*)out, bias,
                                                  8192, 4096, 4096);
}

// Round 5
// 502.709 us; speedup vs baseline: 1.0018x; 1.0018x over previous
//
#include <hip/hip_runtime.h>
#include <hip/hip_bf16.h>
#include <stdint.h>

typedef __attribute__((ext_vector_type(4)))  float f32x4;
typedef __attribute__((ext_vector_type(16))) float f32x16;
typedef __attribute__((ext_vector_type(8)))  short short8v;

typedef __attribute__((address_space(1))) void gvoid;
typedef __attribute__((address_space(3))) void lvoid;

#define GLD16(gp, lp) __builtin_amdgcn_global_load_lds((const gvoid*)(gp), (lvoid*)(lp), 16, 0, 0)

__device__ __forceinline__ unsigned short f2bf(float f) {
    union { float ff; unsigned uu; } a; a.ff = f;
    unsigned u = a.uu;
    u += 0x7FFFu + ((u >> 16) & 1u);   // RNE; inputs finite
    return (unsigned short)(u >> 16);
}

// ---- Ub[o][r] = bf16(U[o][r] * (S[r]+eps[r])), row-major [4096][4096] ----
__global__ __launch_bounds__(256) void prep_u_kernel(
    const float* __restrict__ U, const float* __restrict__ S,
    const float* __restrict__ eps, unsigned short* __restrict__ Ub) {
    long idx = ((long)blockIdx.x * 256 + threadIdx.x) * 8;
    int r = (int)(idx & 4095);
    f32x4 u0 = *(const f32x4*)(U + idx);
    f32x4 u1 = *(const f32x4*)(U + idx + 4);
    f32x4 s0 = *(const f32x4*)(S + r);
    f32x4 s1 = *(const f32x4*)(S + r + 4);
    f32x4 e0 = *(const f32x4*)(eps + r);
    f32x4 e1 = *(const f32x4*)(eps + r + 4);
    union { uint4 v; unsigned short s[8]; } o;
#pragma unroll
    for (int j = 0; j < 4; ++j) {
        o.s[j]     = f2bf(u0[j] * (s0[j] + e0[j]));
        o.s[j + 4] = f2bf(u1[j] * (s1[j] + e1[j]));
    }
    *(uint4*)(Ub + idx) = o.v;
}

// ---- generic fp32 -> bf16 convert, 8 elems/thread ----
__global__ __launch_bounds__(256) void cvt_bf16_kernel(
    const float* __restrict__ src, unsigned short* __restrict__ dst) {
    long idx = ((long)blockIdx.x * 256 + threadIdx.x) * 8;
    f32x4 v0 = *(const f32x4*)(src + idx);
    f32x4 v1 = *(const f32x4*)(src + idx + 4);
    union { uint4 v; unsigned short s[8]; } o;
#pragma unroll
    for (int j = 0; j < 4; ++j) {
        o.s[j]     = f2bf(v0[j]);
        o.s[j + 4] = f2bf(v1[j]);
    }
    *(uint4*)(dst + idx) = o.v;
}

// ---- VtT[k][r] = bf16(Vt[r][k]); 64x64 tiles, padded LDS (conflict-free) ----
__global__ __launch_bounds__(256) void transpose_cvt_kernel(
    const float* __restrict__ src, unsigned short* __restrict__ dst) {
    __shared__ float tile[64][65];
    int tx = threadIdx.x & 63;
    int tq = threadIdx.x >> 6;
    int r0 = blockIdx.y << 6;
    int k0 = blockIdx.x << 6;
#pragma unroll
    for (int i = 0; i < 16; ++i) {
        int row = (i << 2) + tq;
        tile[row][tx] = src[(long)(r0 + row) * 4096 + k0 + tx];
    }
    __syncthreads();
#pragma unroll
    for (int i = 0; i < 16; ++i) {
        int krow = (i << 2) + tq;
        dst[(long)(k0 + krow) * 4096 + r0 + tx] = f2bf(tile[tx][krow]);
    }
}

// =====================================================================
// 256x256-tile 4-phase NT GEMM, 32x32x16 MFMA, stripe-permuted LDS.
// C[M][N] = A[M][K] * B[N][K]^T (+bias). bf16 in, fp32 acc.
// 512 thr = 8 waves (2M x 4N), wave tile 128x64, BK=64, dbuf.
//
// LDS: each chunk (bf,kh) = 16 KB = 16 stripes of 1024B. One stripe ==
// the exact payload of ONE ds_read_b128: A-stripe (wwr,m,ks) at index
// wwr*8+m*2+ks, B-stripe (wwc,nf,ks) at wwc*4+nf*2+ks. Within a stripe,
// lane l reads byte (l&15)*64 + ((l>>4)^((l>>1)&3))*16 — the EXACT
// address pattern measured at ZERO bank conflicts in round 3 (each 8
// consecutive lanes hit 8 distinct bank-quads). Round 4's 32-rows-per-
// read pattern re-created 4-way conflicts (2.5e7) despite per-wave
// balance — rule 21: stage side inverts the permutation via per-lane
// global addresses; global_load_lds dest stays linear (lane*16).
//   Stage inversion (verified by spot checks): lane j of instr w holds
//   row16=j>>2, slot4=j&3; with s=(j>>3)&3, x=(j&3)^s:
//   row = m(w)*32 + (x&1)*16 + (j>>2), kel = ks(w)*16 + (x>>1)*8.
// vmcnt(8) per phase drains exactly the 3-phase-old stage (never 0).
// =====================================================================
#define MM32(a, b, c) __builtin_amdgcn_mfma_f32_32x32x16_bf16(a, b, c, 0, 0, 0)

#define ACH(bf, kh) (As + ((bf) * 2 + (kh)) * 8192)
#define BCH(bf, kh) (Bs + ((bf) * 2 + (kh)) * 8192)

#define STAGE_A(bf, kh, koff) do { \
    const unsigned short* _s = A + gAr + (koff); \
    unsigned short* _d = ACH(bf, kh) + wave * 512; \
    GLD16(_s, _d); GLD16(_s + (long)128 * K, _d + 4096); } while (0)

#define STAGE_B(bf, kh, koff) do { \
    const unsigned short* _s = B + gBr + (koff); \
    unsigned short* _d = BCH(bf, kh) + wave * 512; \
    GLD16(_s, _d); GLD16(_s + (long)128 * K, _d + 4096); } while (0)

// A-frags for one chunk, both k-steps: 8 x ds_read_b128 (stripe reads)
#define LDA32(bf, kh) do { \
    const unsigned short* _p = ACH(bf, kh) + aRd; \
    _Pragma("unroll") \
    for (int _m = 0; _m < 4; ++_m) { \
        aR[0][_m] = *(const short8v*)(_p + _m * 1024); \
        aR[1][_m] = *(const short8v*)(_p + _m * 1024 + 512); } } while (0)

// B-frags for one chunk, both k-steps: 4 x ds_read_b128 (stripe reads)
#define LDB32(bf, kh) do { \
    const unsigned short* _p = BCH(bf, kh) + bRd; \
    _Pragma("unroll") \
    for (int _n = 0; _n < 2; ++_n) { \
        bR[0][_n] = *(const short8v*)(_p + _n * 1024); \
        bR[1][_n] = *(const short8v*)(_p + _n * 1024 + 512); } } while (0)

#define PH_SYNC do { \
    __builtin_amdgcn_s_barrier(); \
    asm volatile("s_waitcnt lgkmcnt(0)" ::: "memory"); \
    __builtin_amdgcn_sched_barrier(0); } while (0)

#define MFMA32 do { \
    __builtin_amdgcn_s_setprio(1); \
    _Pragma("unroll") \
    for (int _ks = 0; _ks < 2; ++_ks) \
    _Pragma("unroll") \
    for (int _m = 0; _m < 4; ++_m) { \
        acc[_m][0] = MM32(aR[_ks][_m], bR[_ks][0], acc[_m][0]); \
        acc[_m][1] = MM32(aR[_ks][_m], bR[_ks][1], acc[_m][1]); \
    } \
    __builtin_amdgcn_s_setprio(0); } while (0)

#define VM8 asm volatile("s_waitcnt vmcnt(8)" ::: "memory")
#define PH_END __builtin_amdgcn_s_barrier()

template<int OUT_BF16, int BIAS>
__global__ __launch_bounds__(512, 2) void gemm256_kernel(
    const unsigned short* __restrict__ A,   // [M][K] bf16 bits
    const unsigned short* __restrict__ B,   // [N][K] bf16 bits
    void* __restrict__ Cv, const float* __restrict__ bias,
    int M, int N, int K) {
    __shared__ unsigned short As[4 * 8192];   // 64 KB
    __shared__ unsigned short Bs[4 * 8192];   // 64 KB

    const int tid  = threadIdx.x;
    const int wave = tid >> 6;
    const int lane = tid & 63;
    const int l5   = lane & 31;
    const int hi   = lane >> 5;

    // XCD-aware bijective swizzle (nwg % 8 == 0 for all launches)
    const int nwg = gridDim.x;
    const int bid = blockIdx.x;
    const int cpx = nwg >> 3;
    const int wg  = (bid & 7) * cpx + (bid >> 3);
    const int ntn = N >> 8;
    const long m0 = (long)(wg / ntn) << 8;
    const long n0 = (long)(wg % ntn) << 8;

    const int wwr = wave >> 2;   // 0..1  (M half)
    const int wwc = wave & 3;    // 0..3  (N quarter)

    // ---- Stage addressing (stripe permutation inverse) ----
    // Instr w = wave stages A-stripe (wwr=0, m=(w>>1)&3, ks=w&1) and
    // B-stripe (wwc=w>>2, nf=(w>>1)&1, ks=w&1); second GLD = +128 rows.
    const int r16 = lane >> 2;
    const int x   = (lane & 3) ^ ((lane >> 3) & 3);
    const int xb0 = x & 1, xb1 = x >> 1;
    const int kel = (wave & 1) * 16 + xb1 * 8;
    const int rowA = ((wave >> 1) & 3) * 32 + xb0 * 16 + r16;
    const int rowB = (wave >> 2) * 64 + ((wave >> 1) & 1) * 32 + xb0 * 16 + r16;
    const long gAr = (m0 + rowA) * K + kel;
    const long gBr = (n0 + rowB) * K + kel;

    // ---- Read addressing: round-3 verified zero-conflict pattern ----
    // lane l -> in-stripe elems (l&15)*32 + ((l>>4)^((l>>1)&3))*8
    const int rdoff = (lane & 15) * 32 + (((lane >> 4) ^ ((lane >> 1) & 3)) * 8);
    const int aRd = wwr * 4096 + rdoff;   // + m*1024 + ks*512
    const int bRd = wwc * 2048 + rdoff;   // + nf*1024 + ks*512

    f32x16  acc[4][2] = {};
    short8v aR[2][4], bR[2][2];

    // Prologue: buf0.kh0, buf0.kh1, buf1.kh0 (A+B each = 4 loads).
    STAGE_A(0, 0, 0);  STAGE_B(0, 0, 0);
    STAGE_A(0, 1, 32); STAGE_B(0, 1, 32);
    STAGE_A(1, 0, 64); STAGE_B(1, 0, 64);
    VM8;                         // buf0.kh0 landed
    __builtin_amdgcn_s_barrier();

    const int nIter = K >> 7;    // 2 K-tiles (BK=64) per iteration
    for (int i = 0; i < nIter; ++i) {
        const int kA = 128 * i + 96;                  // buf1.kh1 (in-bounds)
        int k3 = 128 * i + 128; if (k3 >= K) k3 -= K; // next buf0.kh0 (wrap: dead)
        int k5 = 128 * i + 160; if (k5 >= K) k5 -= K; // next buf0.kh1
        int k7 = 128 * i + 192; if (k7 >= K) k7 -= K; // next buf1.kh0

        LDA32(0, 0); LDB32(0, 0); STAGE_A(1, 1, kA); STAGE_B(1, 1, kA);   // P1
        PH_SYNC; MFMA32; VM8; PH_END;
        LDA32(0, 1); LDB32(0, 1); STAGE_A(0, 0, k3); STAGE_B(0, 0, k3);   // P2
        PH_SYNC; MFMA32; VM8; PH_END;
        LDA32(1, 0); LDB32(1, 0); STAGE_A(0, 1, k5); STAGE_B(0, 1, k5);   // P3
        PH_SYNC; MFMA32; VM8; PH_END;
        LDA32(1, 1); LDB32(1, 1); STAGE_A(1, 0, k7); STAGE_B(1, 0, k7);   // P4
        PH_SYNC; MFMA32; VM8; PH_END;
    }

    // Epilogue: 32x32 C/D layout (m74/m101): col = lane&31,
    // row = (reg&3) + 8*(reg>>2) + 4*(lane>>5)
#pragma unroll
    for (int nf = 0; nf < 2; ++nf) {
        const int col = (int)n0 + wwc * 64 + nf * 32 + l5;
        float bv = BIAS ? bias[col] : 0.0f;
#pragma unroll
        for (int mf = 0; mf < 4; ++mf) {
            f32x16 v = acc[mf][nf];
            const long rb = m0 + wwr * 128 + mf * 32 + hi * 4;
#pragma unroll
            for (int r = 0; r < 16; ++r) {
                long row = rb + (r & 3) + 8 * (r >> 2);
                float val = v[r] + bv;
                long off = row * N + col;
                if (OUT_BF16) ((unsigned short*)Cv)[off] = f2bf(val);
                else          ((float*)Cv)[off] = val;
            }
        }
    }
}

extern "C" void kernel_launch(void* const* d_in, const int* in_sizes, int n_in,
                              void* d_out, int out_size, void* d_ws, size_t ws_size,
                              hipStream_t stream) {
    const float* x    = (const float*)d_in[0];   // [4,2048,4096] = [8192][4096]
    const float* U    = (const float*)d_in[1];   // [4096][4096]
    const float* S    = (const float*)d_in[2];   // [4096]
    const float* Vt   = (const float*)d_in[3];   // [4096][4096]
    const float* eps  = (const float*)d_in[4];   // [4096]
    const float* bias = (const float*)d_in[5];   // [4096]
    float* out = (float*)d_out;                  // [8192][4096] fp32

    char* ws = (char*)d_ws;
    unsigned short* Ub  = (unsigned short*)(ws);                       // 32 MB
    unsigned short* VtT = (unsigned short*)(ws + (size_t)(32 << 20));  // 32 MB
    unsigned short* Wb  = (unsigned short*)(ws + (size_t)(64 << 20));  // 32 MB
    unsigned short* Xb  = (unsigned short*)(ws);  // 64 MB, reuses Ub+VtT after GEMM1

    // 1) Ub = bf16(U * (S+eps))            [o][r]
    prep_u_kernel<<<8192, 256, 0, stream>>>(U, S, eps, Ub);
    // 2) VtT = bf16(Vt^T)                  [k][r]
    transpose_cvt_kernel<<<dim3(64, 64), 256, 0, stream>>>(Vt, VtT);
    // 3) Wb[o][k] = Ub @ VtT^T             (NT, K=r)  -> 256 wg
    gemm256_kernel<1, 0><<<256, 512, 0, stream>>>(Ub, VtT, (void*)Wb, nullptr,
                                                  4096, 4096, 4096);
    // 4) Xb = bf16(x)                      [m][k]  (overwrites Ub/VtT — now dead)
    cvt_bf16_kernel<<<16384, 256, 0, stream>>>(x, Xb);
    // 5) out[m][o] = Xb @ Wb^T + bias      (NT, K=k)  -> 512 wg
    gemm256_kernel<0, 1><<<512, 512, 0, stream>>>(Xb, Wb, (void*)out, bias,
                                                  8192, 4096, 4096);
}

// Round 6
// 456.757 us; speedup vs baseline: 1.1026x; 1.1006x over previous
//
#include <hip/hip_runtime.h>
#include <hip/hip_bf16.h>
#include <stdint.h>

typedef __attribute__((ext_vector_type(4))) float f32x4;
typedef __attribute__((ext_vector_type(8))) short short8v;

typedef __attribute__((address_space(1))) void gvoid;
typedef __attribute__((address_space(3))) void lvoid;

#define GLD16(gp, lp) __builtin_amdgcn_global_load_lds((const gvoid*)(gp), (lvoid*)(lp), 16, 0, 0)

__device__ __forceinline__ unsigned short f2bf(float f) {
    union { float ff; unsigned uu; } a; a.ff = f;
    unsigned u = a.uu;
    u += 0x7FFFu + ((u >> 16) & 1u);   // RNE; inputs finite
    return (unsigned short)(u >> 16);
}

// ---- Ub[o][r] = bf16(U[o][r] * (S[r]+eps[r])), row-major [4096][4096] ----
__global__ __launch_bounds__(256) void prep_u_kernel(
    const float* __restrict__ U, const float* __restrict__ S,
    const float* __restrict__ eps, unsigned short* __restrict__ Ub) {
    long idx = ((long)blockIdx.x * 256 + threadIdx.x) * 8;
    int r = (int)(idx & 4095);
    f32x4 u0 = *(const f32x4*)(U + idx);
    f32x4 u1 = *(const f32x4*)(U + idx + 4);
    f32x4 s0 = *(const f32x4*)(S + r);
    f32x4 s1 = *(const f32x4*)(S + r + 4);
    f32x4 e0 = *(const f32x4*)(eps + r);
    f32x4 e1 = *(const f32x4*)(eps + r + 4);
    union { uint4 v; unsigned short s[8]; } o;
#pragma unroll
    for (int j = 0; j < 4; ++j) {
        o.s[j]     = f2bf(u0[j] * (s0[j] + e0[j]));
        o.s[j + 4] = f2bf(u1[j] * (s1[j] + e1[j]));
    }
    *(uint4*)(Ub + idx) = o.v;
}

// ---- generic fp32 -> bf16 convert, 8 elems/thread ----
__global__ __launch_bounds__(256) void cvt_bf16_kernel(
    const float* __restrict__ src, unsigned short* __restrict__ dst) {
    long idx = ((long)blockIdx.x * 256 + threadIdx.x) * 8;
    f32x4 v0 = *(const f32x4*)(src + idx);
    f32x4 v1 = *(const f32x4*)(src + idx + 4);
    union { uint4 v; unsigned short s[8]; } o;
#pragma unroll
    for (int j = 0; j < 4; ++j) {
        o.s[j]     = f2bf(v0[j]);
        o.s[j + 4] = f2bf(v1[j]);
    }
    *(uint4*)(dst + idx) = o.v;
}

// ---- VtT[k][r] = bf16(Vt[r][k]); 64x64 tiles, padded LDS (conflict-free) ----
__global__ __launch_bounds__(256) void transpose_cvt_kernel(
    const float* __restrict__ src, unsigned short* __restrict__ dst) {
    __shared__ float tile[64][65];
    int tx = threadIdx.x & 63;
    int tq = threadIdx.x >> 6;
    int r0 = blockIdx.y << 6;
    int k0 = blockIdx.x << 6;
#pragma unroll
    for (int i = 0; i < 16; ++i) {
        int row = (i << 2) + tq;
        tile[row][tx] = src[(long)(r0 + row) * 4096 + k0 + tx];
    }
    __syncthreads();
#pragma unroll
    for (int i = 0; i < 16; ++i) {
        int krow = (i << 2) + tq;
        dst[(long)(k0 + krow) * 4096 + r0 + tx] = f2bf(tile[tx][krow]);
    }
}

// =====================================================================
// 256x256-tile 8-phase NT GEMM — round-3 kernel (best: 265us GEMM2,
// 0 bank conflicts) with ONE change: sched_barrier(0) REMOVED from
// PH_SYNC. It was a total per-phase scheduling wall (m141 failure mode:
// order-pinning -> 510 TF); the m201 reference template (62% MfmaUtil,
// same geometry) has none. Hazards remain covered:
//  - write-after-read: each wave's ds_reads complete before its own
//    lgkmcnt(0) ("memory" clobber pins loads) -> before PH_END ->
//    before any wave's overwriting STAGE next phase.
//  - read-after-stage: vmcnt(4) at P4/P8 only; every chunk lands >=2
//    phases + one drain before its first reader.
// XOR swizzle slot ^= (row>>1)&3 both-sides (rule 21): 0 conflicts.
// =====================================================================
#define MM(a, b, c) __builtin_amdgcn_mfma_f32_16x16x32_bf16(a, b, c, 0, 0, 0)

#define ACH(bf, kh) (As + ((bf) * 2 + (kh)) * 8192)
#define BCH(bf, kh) (Bs + ((bf) * 2 + (kh)) * 8192)

#define STAGE_A(bf, kh, koff) do { \
    const unsigned short* _s = A + gAr + (koff); \
    unsigned short* _d = ACH(bf, kh) + wave * 512; \
    GLD16(_s, _d); GLD16(_s + (long)128 * K, _d + 4096); } while (0)

#define STAGE_B(bf, kh, koff) do { \
    const unsigned short* _s = B + gBr + (koff); \
    unsigned short* _d = BCH(bf, kh) + wave * 512; \
    GLD16(_s, _d); GLD16(_s + (long)128 * K, _d + 4096); } while (0)

#define LOAD_A(bf, ks, mh) do { \
    const unsigned short* _p = ACH(bf, ks) + aBase + (mh) * 2048; \
    _Pragma("unroll") \
    for (int _m = 0; _m < 4; ++_m) aR[_m] = *(const short8v*)(_p + _m * 512); } while (0)

#define READ_B(bf, ks) do { \
    const unsigned short* _p = BCH(bf, ks) + bBase; \
    _Pragma("unroll") \
    for (int _n = 0; _n < 4; ++_n) bR[_n] = *(const short8v*)(_p + _n * 512); } while (0)

// NOTE: no sched_barrier(0) here — the one delta vs round 3.
#define PH_SYNC do { \
    __builtin_amdgcn_s_barrier(); \
    asm volatile("s_waitcnt lgkmcnt(0)" ::: "memory"); } while (0)

#define MFMA16(mh) do { \
    __builtin_amdgcn_s_setprio(1); \
    _Pragma("unroll") \
    for (int _m = 0; _m < 4; ++_m) { \
        acc[(mh) * 4 + _m][0] = MM(aR[_m], bR[0], acc[(mh) * 4 + _m][0]); \
        acc[(mh) * 4 + _m][1] = MM(aR[_m], bR[1], acc[(mh) * 4 + _m][1]); \
        acc[(mh) * 4 + _m][2] = MM(aR[_m], bR[2], acc[(mh) * 4 + _m][2]); \
        acc[(mh) * 4 + _m][3] = MM(aR[_m], bR[3], acc[(mh) * 4 + _m][3]); \
    } \
    __builtin_amdgcn_s_setprio(0); } while (0)

#define VM4 asm volatile("s_waitcnt vmcnt(4)" ::: "memory")
#define PH_END __builtin_amdgcn_s_barrier()

template<int OUT_BF16, int BIAS>
__global__ __launch_bounds__(512, 2) void gemm256_kernel(
    const unsigned short* __restrict__ A,   // [M][K] bf16 bits
    const unsigned short* __restrict__ B,   // [N][K] bf16 bits
    void* __restrict__ Cv, const float* __restrict__ bias,
    int M, int N, int K) {
    __shared__ unsigned short As[4 * 8192];   // 64 KB
    __shared__ unsigned short Bs[4 * 8192];   // 64 KB

    const int tid  = threadIdx.x;
    const int wave = tid >> 6;
    const int lane = tid & 63;
    const int fr   = lane & 15;
    const int fq   = lane >> 4;

    // XCD-aware bijective swizzle (nwg % 8 == 0 for all launches)
    const int nwg = gridDim.x;
    const int bid = blockIdx.x;
    const int cpx = nwg >> 3;
    const int wg  = (bid & 7) * cpx + (bid >> 3);
    const int ntn = N >> 8;
    const long m0 = (long)(wg / ntn) << 8;
    const long n0 = (long)(wg % ntn) << 8;

    const int wwr = wave >> 2;   // 0..1  (M half)
    const int wwc = wave & 3;    // 0..3  (N quarter)

    // Stage addressing: chunk = [256 rows][32 k] bf16, 1024 slots of 16B.
    // slot si = j*512 + wave*64 + lane -> row si>>2, in-row slot si&3.
    // Inverse swizzle on the GLOBAL side: src slot = (si&3) ^ ((row>>1)&3).
    // ((rS+128)>>1)&3 == (rS>>1)&3, so one XOR serves both row-halves.
    const int  rS  = tid >> 2;                        // rows rS and rS+128
    const int  sS  = (tid & 3) ^ ((rS >> 1) & 3);
    const long gAr = (m0 + rS) * K + sS * 8;
    const long gBr = (n0 + rS) * K + sS * 8;

    // ds_read addressing (swizzled): elem = row*32 + ((fq ^ ((row>>1)&3))*8)
    // row = (mult of 16) + fr  ->  (row>>1)&3 == (fr>>1)&3
    const int swz   = (fq ^ ((fr >> 1) & 3)) * 8;
    const int aBase = (wwr * 128 + fr) * 32 + swz;
    const int bBase = (wwc * 64 + fr) * 32 + swz;

    f32x4  acc[8][4] = {};
    short8v aR[4], bR[4];

    // Prologue: kt0 both halves + kt1.kh0, then vmcnt(4) -> buf0 landed.
    STAGE_A(0, 0, 0);  STAGE_B(0, 0, 0);
    STAGE_A(0, 1, 32); STAGE_B(0, 1, 32);
    STAGE_A(1, 0, 64); STAGE_B(1, 0, 64);
    VM4;
    __builtin_amdgcn_s_barrier();

    const int nIter = K >> 7;   // 2 K-tiles (BK=64) per iteration
    for (int i = 0; i < nIter; ++i) {
        const int kt1off = 128 * i + 96;              // kt1.kh1 (always in-bounds)
        int k3 = 128 * i + 128; if (k3 >= K) k3 -= K; // kt0+2 . kh0 (wrap: dead data)
        int k5 = 128 * i + 160; if (k5 >= K) k5 -= K; // kt0+2 . kh1
        int k7 = 128 * i + 192; if (k7 >= K) k7 -= K; // kt1+2 . kh0

        // ---- K-tile kt0 (buf 0) ----
        LOAD_A(0, 0, 0); READ_B(0, 0); STAGE_A(1, 1, kt1off);   // P1
        PH_SYNC; MFMA16(0); PH_END;
        LOAD_A(0, 0, 1); STAGE_B(1, 1, kt1off);                 // P2
        PH_SYNC; MFMA16(1); PH_END;
        LOAD_A(0, 1, 0); READ_B(0, 1); STAGE_A(0, 0, k3);       // P3
        PH_SYNC; MFMA16(0); PH_END;
        LOAD_A(0, 1, 1); STAGE_B(0, 0, k3);                     // P4
        PH_SYNC; MFMA16(1); VM4; PH_END;
        // ---- K-tile kt1 (buf 1) ----
        LOAD_A(1, 0, 0); READ_B(1, 0); STAGE_A(0, 1, k5);       // P5
        PH_SYNC; MFMA16(0); PH_END;
        LOAD_A(1, 0, 1); STAGE_B(0, 1, k5);                     // P6
        PH_SYNC; MFMA16(1); PH_END;
        LOAD_A(1, 1, 0); READ_B(1, 1); STAGE_A(1, 0, k7);       // P7
        PH_SYNC; MFMA16(0); PH_END;
        LOAD_A(1, 1, 1); STAGE_B(1, 0, k7);                     // P8
        PH_SYNC; MFMA16(1); VM4; PH_END;
    }

    // Epilogue: C/D layout col = lane&15, row = (lane>>4)*4 + j
#pragma unroll
    for (int nf = 0; nf < 4; ++nf) {
        const int col = (int)n0 + wwc * 64 + nf * 16 + fr;
        float bv = BIAS ? bias[col] : 0.0f;
#pragma unroll
        for (int mf = 0; mf < 8; ++mf) {
            f32x4 v = acc[mf][nf];
            long rowb = m0 + wwr * 128 + mf * 16 + fq * 4;
#pragma unroll
            for (int j = 0; j < 4; ++j) {
                float val = v[j] + bv;
                long off = (rowb + j) * N + col;
                if (OUT_BF16) ((unsigned short*)Cv)[off] = f2bf(val);
                else          ((float*)Cv)[off] = val;
            }
        }
    }
}

extern "C" void kernel_launch(void* const* d_in, const int* in_sizes, int n_in,
                              void* d_out, int out_size, void* d_ws, size_t ws_size,
                              hipStream_t stream) {
    const float* x    = (const float*)d_in[0];   // [4,2048,4096] = [8192][4096]
    const float* U    = (const float*)d_in[1];   // [4096][4096]
    const float* S    = (const float*)d_in[2];   // [4096]
    const float* Vt   = (const float*)d_in[3];   // [4096][4096]
    const float* eps  = (const float*)d_in[4];   // [4096]
    const float* bias = (const float*)d_in[5];   // [4096]
    float* out = (float*)d_out;                  // [8192][4096] fp32

    char* ws = (char*)d_ws;
    unsigned short* Ub  = (unsigned short*)(ws);                       // 32 MB
    unsigned short* VtT = (unsigned short*)(ws + (size_t)(32 << 20));  // 32 MB
    unsigned short* Wb  = (unsigned short*)(ws + (size_t)(64 << 20));  // 32 MB
    unsigned short* Xb  = (unsigned short*)(ws);  // 64 MB, reuses Ub+VtT after GEMM1

    // 1) Ub = bf16(U * (S+eps))            [o][r]
    prep_u_kernel<<<8192, 256, 0, stream>>>(U, S, eps, Ub);
    // 2) VtT = bf16(Vt^T)                  [k][r]
    transpose_cvt_kernel<<<dim3(64, 64), 256, 0, stream>>>(Vt, VtT);
    // 3) Wb[o][k] = Ub @ VtT^T             (NT, K=r)  -> 256 wg
    gemm256_kernel<1, 0><<<256, 512, 0, stream>>>(Ub, VtT, (void*)Wb, nullptr,
                                                  4096, 4096, 4096);
    // 4) Xb = bf16(x)                      [m][k]  (overwrites Ub/VtT — now dead)
    cvt_bf16_kernel<<<16384, 256, 0, stream>>>(x, Xb);
    // 5) out[m][o] = Xb @ Wb^T + bias      (NT, K=k)  -> 512 wg
    gemm256_kernel<0, 1><<<512, 512, 0, stream>>>(Xb, Wb, (void*)out, bias,
                                                  8192, 4096, 4096);
}